// Round 13
// baseline (229.592 us; speedup 1.0000x reference)
//
#include <hip/hip_runtime.h>
#include <hip/hip_bf16.h>

// ---------- types ----------
typedef __attribute__((ext_vector_type(8))) short bf16x8;   // 8 bf16 in 4 VGPRs
typedef __attribute__((ext_vector_type(4))) float f32x4;    // MFMA accumulator
typedef __attribute__((ext_vector_type(8))) unsigned short u16x8;

static __device__ __forceinline__ unsigned short f2bf(float f) {
    union { float f; unsigned int u; } v; v.f = f;
    unsigned int u = v.u;
    u += 0x7FFFu + ((u >> 16) & 1u);
    return (unsigned short)(u >> 16);
}

// ---------- K1: fused convert+transpose+GEMM ----------
// V[b][m][n] = sum_k W[m][k]*x_vit[b][k][n] + bias[m]   (fp32 in, fp32 out)
// Staging converts fp32->bf16 (same RNE f2bf as the verified prep) on the fly:
//   A: thread(ka=t&3, ma=t>>2) loads W[m0+ma][k0+ka*8..+7] as 2 float4s.
//   B: thread(kb=t>>6, nb=t&63) loads x_vit[b][k0+kb*8+j][n0+nb] j=0..7 —
//      per-instr all 64 lanes read 64 consecutive pixels of one k-row (256B).
// LDS layout, XOR swizzle, double-buffer, single barrier/K-step, MFMA core and
// epilogue are BYTE-IDENTICAL to the round-7/10 verified gemm_bf16.
// Eliminates the prep kernel and the Xt(16MiB)/Wbf round-trips entirely.
__global__ void __launch_bounds__(256) gemm_fused(const float* __restrict__ W,    // [256][512]
                                                  const float* __restrict__ Xv,   // [8][512][1024]
                                                  const float* __restrict__ bias, // [256]
                                                  float* __restrict__ V) {        // [8][256][1024]
    __shared__ __align__(16) unsigned short As[2][4 * 64 * 8];  // [buf][koct][m][8]
    __shared__ __align__(16) unsigned short Bs[2][4 * 64 * 8];  // [buf][koct][n][8]

    int b  = blockIdx.z;
    int m0 = blockIdx.y * 64;
    int n0 = blockIdx.x * 64;
    int t  = threadIdx.x;
    int wave = t >> 6;
    int lane = t & 63;
    int wm = (wave >> 1) * 32;
    int wn = (wave & 1) * 32;
    int l15  = lane & 15;
    int quad = lane >> 4;

    // A staging coords (identical role to verified koct/mrow)
    int ka = t & 3;
    int ma = t >> 2;
    const float* Ag = W + (size_t)(m0 + ma) * 512 + (ka << 3);
    int stA = (ka * 512 + ma * 8) ^ (ka * 8);

    // B staging coords (transposed source read; same LDS slot formula)
    int kb = t >> 6;
    int nb = t & 63;
    const float* Bg = Xv + ((size_t)b * 512 + (kb << 3)) * 1024 + n0 + nb;
    int stB = (kb * 512 + nb * 8) ^ (kb * 8);

    // swizzled read slots (byte-identical to verified kernel)
    int ia0 = (quad * 512 + (wm      + l15) * 8) ^ (quad * 8);
    int ia1 = (quad * 512 + (wm + 16 + l15) * 8) ^ (quad * 8);
    int ib0 = (quad * 512 + (wn      + l15) * 8) ^ (quad * 8);
    int ib1 = (quad * 512 + (wn + 16 + l15) * 8) ^ (quad * 8);

    f32x4 acc[2][2] = {};

    // load + convert one K-tile into registers
    u16x8 ra, rb;
    {
        float4 x = *(const float4*)(Ag);
        float4 y = *(const float4*)(Ag + 4);
        ra[0] = (short)f2bf(x.x); ra[1] = (short)f2bf(x.y);
        ra[2] = (short)f2bf(x.z); ra[3] = (short)f2bf(x.w);
        ra[4] = (short)f2bf(y.x); ra[5] = (short)f2bf(y.y);
        ra[6] = (short)f2bf(y.z); ra[7] = (short)f2bf(y.w);
        #pragma unroll
        for (int j = 0; j < 8; ++j) rb[j] = (short)f2bf(Bg[(size_t)j * 1024]);
    }
    *(u16x8*)(As[0] + stA) = ra;
    *(u16x8*)(Bs[0] + stB) = rb;
    __syncthreads();

    for (int k0 = 0; k0 < 512; k0 += 32) {
        int p = (k0 >> 5) & 1;
        bool more = (k0 + 32) < 512;
        if (more) {                           // prefetch + convert next K-tile
            float4 x = *(const float4*)(Ag + k0 + 32);
            float4 y = *(const float4*)(Ag + k0 + 36);
            ra[0] = (short)f2bf(x.x); ra[1] = (short)f2bf(x.y);
            ra[2] = (short)f2bf(x.z); ra[3] = (short)f2bf(x.w);
            ra[4] = (short)f2bf(y.x); ra[5] = (short)f2bf(y.y);
            ra[6] = (short)f2bf(y.z); ra[7] = (short)f2bf(y.w);
            #pragma unroll
            for (int j = 0; j < 8; ++j) rb[j] = (short)f2bf(Bg[(size_t)(k0 + 32 + j) * 1024]);
        }

        bf16x8 a0 = *(const bf16x8*)(As[p] + ia0);
        bf16x8 a1 = *(const bf16x8*)(As[p] + ia1);
        bf16x8 b0 = *(const bf16x8*)(Bs[p] + ib0);
        bf16x8 b1 = *(const bf16x8*)(Bs[p] + ib1);

        acc[0][0] = __builtin_amdgcn_mfma_f32_16x16x32_bf16(a0, b0, acc[0][0], 0, 0, 0);
        acc[0][1] = __builtin_amdgcn_mfma_f32_16x16x32_bf16(a0, b1, acc[0][1], 0, 0, 0);
        acc[1][0] = __builtin_amdgcn_mfma_f32_16x16x32_bf16(a1, b0, acc[1][0], 0, 0, 0);
        acc[1][1] = __builtin_amdgcn_mfma_f32_16x16x32_bf16(a1, b1, acc[1][1], 0, 0, 0);

        if (more) {                           // store next tile into other buffer
            *(u16x8*)(As[p ^ 1] + stA) = ra;
            *(u16x8*)(Bs[p ^ 1] + stB) = rb;
        }
        __syncthreads();
    }

    #pragma unroll
    for (int mi = 0; mi < 2; ++mi)
        #pragma unroll
        for (int ni = 0; ni < 2; ++ni)
            #pragma unroll
            for (int r = 0; r < 4; ++r) {
                int gm = m0 + wm + mi * 16 + quad * 4 + r;
                int gn = n0 + wn + ni * 16 + l15;
                V[((size_t)b * 256 + gm) * 1024 + gn] = acc[mi][ni][r] + bias[gm];
            }
}

// ---------- K2: fused cosine v3 (byte-identical to round-10 PASSING version) ----------
__global__ void __launch_bounds__(256) fused_cos(const float* __restrict__ xcnn, // [8][256][128][128]
                                                 const float* __restrict__ V,    // [8][256][32][32]
                                                 float* __restrict__ out) {      // [8][1][128][128]
    __shared__ float sh[9216];   // 36 KB: phase1/2 = Vblend[256][36]; phase3 = red[8*385]

    int bh = blockIdx.x;
    int b  = bh >> 7;
    int h  = bh & 127;
    int t  = threadIdx.x;
    int q  = t & 31;     // w-quad: pixels 4q..4q+3
    int cs = t >> 5;     // channel slice: channels cs*32..cs*32+31

    // ----- row interpolation -----
    float sy = (h + 0.5f) * 0.25f - 0.5f;
    float fy = floorf(sy);
    float dy = sy - fy;
    int y0 = max(0, min(31, (int)fy));
    int y1 = max(0, min(31, (int)fy + 1));
    float ry = dy, ry0 = 1.f - dy;

    // ----- phase 1: stage blended V rows in LDS -----
    {
        int ch8 = t >> 3;          // 0..31
        int c4  = (t & 7) << 2;    // 0,4,...,28
        #pragma unroll
        for (int p = 0; p < 8; ++p) {
            int ch = p * 32 + ch8;
            const float* vr = V + ((size_t)(b * 256 + ch) * 1024);
            float4 top = *(const float4*)(vr + y0 * 32 + c4);
            float4 bot = *(const float4*)(vr + y1 * 32 + c4);
            float4 bl;
            bl.x = ry0 * top.x + ry * bot.x;
            bl.y = ry0 * top.y + ry * bot.y;
            bl.z = ry0 * top.z + ry * bot.z;
            bl.w = ry0 * top.w + ry * bot.w;
            *(float4*)&sh[ch * 36 + c4] = bl;
        }
    }
    __syncthreads();

    // ----- column weights per pixel, folded with edge clamp -----
    int cb = max(0, min(28, q - 1));
    float a[4][4];
    #pragma unroll
    for (int px = 0; px < 4; ++px) {
        #pragma unroll
        for (int j = 0; j < 4; ++j) a[px][j] = 0.f;
        int w = q * 4 + px;
        float sx = (w + 0.5f) * 0.25f - 0.5f;
        float fx = floorf(sx);
        float dx = sx - fx;
        int x0 = max(0, min(31, (int)fx));
        int x1 = max(0, min(31, (int)fx + 1));
        a[px][x0 - cb] += 1.f - dx;
        a[px][x1 - cb] += dx;
    }

    const float* xp = xcnn + ((size_t)(b * 256 + cs * 32) * 16384) + h * 128 + q * 4;

    float dot[4] = {0.f, 0.f, 0.f, 0.f};
    float nx [4] = {0.f, 0.f, 0.f, 0.f};
    float nv [4] = {0.f, 0.f, 0.f, 0.f};

    #pragma unroll 8
    for (int c = 0; c < 32; ++c) {
        float4 xv = *(const float4*)(xp + (size_t)c * 16384);
        const float* vl = sh + (cs * 32 + c) * 36 + cb;
        float v0 = vl[0], v1 = vl[1], v2 = vl[2], v3 = vl[3];
        float xs[4] = {xv.x, xv.y, xv.z, xv.w};
        #pragma unroll
        for (int px = 0; px < 4; ++px) {
            float v = a[px][0] * v0 + a[px][1] * v1 + a[px][2] * v2 + a[px][3] * v3;
            dot[px] += xs[px] * v;
            nx [px] += xs[px] * xs[px];
            nv [px] += v * v;
        }
    }

    // ----- phase 3: cross-slice reduction (red aliases sh; barrier first) -----
    __syncthreads();
    float* my = sh + cs * 385;
    #pragma unroll
    for (int px = 0; px < 4; ++px) {
        int o = (q * 4 + px) * 3;
        my[o + 0] = dot[px];
        my[o + 1] = nx[px];
        my[o + 2] = nv[px];
    }
    __syncthreads();

    if (t < 128) {
        int px = t & 3;
        int q2 = t >> 2;
        int o  = (q2 * 4 + px) * 3;
        float d = 0.f, sx2 = 0.f, sv2 = 0.f;
        #pragma unroll
        for (int s = 0; s < 8; ++s) {
            d   += sh[s * 385 + o + 0];
            sx2 += sh[s * 385 + o + 1];
            sv2 += sh[s * 385 + o + 2];
        }
        out[(size_t)b * 16384 + h * 128 + q2 * 4 + px] =
            d / (sqrtf(sx2) * sqrtf(sv2) + 1e-8f);
    }
}

extern "C" void kernel_launch(void* const* d_in, const int* in_sizes, int n_in,
                              void* d_out, int out_size, void* d_ws, size_t ws_size,
                              hipStream_t stream) {
    const float* x_cnn = (const float*)d_in[0];  // [8][256][128][128]
    const float* x_vit = (const float*)d_in[1];  // [8][512][32][32]
    const float* W     = (const float*)d_in[2];  // [256][512]
    const float* bias  = (const float*)d_in[3];  // [256]
    float* out = (float*)d_out;                  // [8][1][128][128] fp32

    float* V = (float*)d_ws;                     // 8*256*1024 f32 = 8 MB (only ws use)

    gemm_fused<<<dim3(16, 4, 8), 256, 0, stream>>>(W, x_vit, bias, V);
    fused_cos<<<1024, 256, 0, stream>>>(x_cnn, V, out);
}

// Round 14
// 218.951 us; speedup vs baseline: 1.0486x; 1.0486x over previous
//
#include <hip/hip_runtime.h>
#include <hip/hip_bf16.h>

// ---------- types ----------
typedef __attribute__((ext_vector_type(8))) short bf16x8;   // 8 bf16 in 4 VGPRs
typedef __attribute__((ext_vector_type(4))) float f32x4;    // MFMA accumulator
typedef __attribute__((ext_vector_type(8))) unsigned short u16x8;
typedef __attribute__((ext_vector_type(4), aligned(4))) float f32x4u;  // dword-aligned vec load

static __device__ __forceinline__ unsigned short f2bf(float f) {
    union { float f; unsigned int u; } v; v.f = f;
    unsigned int u = v.u;
    u += 0x7FFFu + ((u >> 16) & 1u);
    return (unsigned short)(u >> 16);
}

// ---------- K1: fused prep (verified 220.5 µs config, round 7) ----------
// blocks [0,1024): transpose x_vit fp32[8][512][1024] -> Xt bf16[8][1024][512]
// blocks [1024,1152): W fp32[256][512] -> bf16
__global__ void __launch_bounds__(256) prep(const float* __restrict__ X,
                                            unsigned short* __restrict__ Xt,
                                            const float* __restrict__ W,
                                            unsigned short* __restrict__ Wbf) {
    __shared__ unsigned short ls[64][65];   // [p][c], padded
    int blk = blockIdx.x;
    int t   = threadIdx.x;

    if (blk >= 1024) {                      // ---- W convert path (no barrier) ----
        int i = ((blk - 1024) * 256 + t) * 4;   // 131072 elems, 128 blocks
        float4 v = *(const float4*)(W + i);
        ushort4 o;
        o.x = f2bf(v.x); o.y = f2bf(v.y); o.z = f2bf(v.z); o.w = f2bf(v.w);
        *(ushort4*)(Wbf + i) = o;
        return;
    }

    int b  = blk >> 7;
    int c0 = ((blk >> 4) & 7) * 64;
    int p0 = (blk & 15) * 64;

    const float* src = X + ((size_t)b * 512 + c0) * 1024 + p0;
    int cc = t >> 4;          // 0..15
    int p4 = (t & 15) << 2;   // 0..60
    #pragma unroll
    for (int i = 0; i < 4; ++i) {
        int c = cc + i * 16;
        float4 v = *(const float4*)(src + (size_t)c * 1024 + p4);
        ls[p4 + 0][c] = f2bf(v.x);
        ls[p4 + 1][c] = f2bf(v.y);
        ls[p4 + 2][c] = f2bf(v.z);
        ls[p4 + 3][c] = f2bf(v.w);
    }
    __syncthreads();

    unsigned short* dst = Xt + ((size_t)b * 1024 + p0) * 512 + c0;
    int pp  = t >> 2;         // 0..63
    int c16 = (t & 3) << 4;   // 0,16,32,48
    u16x8 w0, w1;
    #pragma unroll
    for (int j = 0; j < 8; ++j) { w0[j] = ls[pp][c16 + j]; w1[j] = ls[pp][c16 + 8 + j]; }
    *(u16x8*)(dst + (size_t)pp * 512 + c16)     = w0;
    *(u16x8*)(dst + (size_t)pp * 512 + c16 + 8) = w1;
}

// ---------- K2: gemm (verified 220.5 µs config, round 7) ----------
__global__ void __launch_bounds__(256) gemm_bf16(const unsigned short* __restrict__ Wbf,
                                                 const unsigned short* __restrict__ Xt,
                                                 const float* __restrict__ bias,
                                                 float* __restrict__ V) {
    __shared__ __align__(16) unsigned short As[2][4 * 64 * 8];  // [buf][koct][m][8]
    __shared__ __align__(16) unsigned short Bs[2][4 * 64 * 8];  // [buf][koct][n][8]

    int b  = blockIdx.z;
    int m0 = blockIdx.y * 64;
    int n0 = blockIdx.x * 64;
    int t  = threadIdx.x;
    int wave = t >> 6;
    int lane = t & 63;
    int wm = (wave >> 1) * 32;
    int wn = (wave & 1) * 32;
    int l15  = lane & 15;
    int quad = lane >> 4;

    int koct = t & 3;
    int mrow = t >> 2;

    const unsigned short* Aglob = Wbf + (size_t)(m0 + mrow) * 512 + (koct << 3);
    const unsigned short* Bglob = Xt + ((size_t)b * 1024 + n0 + mrow) * 512 + (koct << 3);
    int stIdx = (koct * 512 + mrow * 8) ^ (koct * 8);

    int ia0 = (quad * 512 + (wm      + l15) * 8) ^ (quad * 8);
    int ia1 = (quad * 512 + (wm + 16 + l15) * 8) ^ (quad * 8);
    int ib0 = (quad * 512 + (wn      + l15) * 8) ^ (quad * 8);
    int ib1 = (quad * 512 + (wn + 16 + l15) * 8) ^ (quad * 8);

    f32x4 acc[2][2] = {};

    u16x8 ra = *(const u16x8*)(Aglob);
    u16x8 rb = *(const u16x8*)(Bglob);
    *(u16x8*)(As[0] + stIdx) = ra;
    *(u16x8*)(Bs[0] + stIdx) = rb;
    __syncthreads();

    for (int k0 = 0; k0 < 512; k0 += 32) {
        int p = (k0 >> 5) & 1;
        bool more = (k0 + 32) < 512;
        if (more) {
            ra = *(const u16x8*)(Aglob + k0 + 32);
            rb = *(const u16x8*)(Bglob + k0 + 32);
        }

        bf16x8 a0 = *(const bf16x8*)(As[p] + ia0);
        bf16x8 a1 = *(const bf16x8*)(As[p] + ia1);
        bf16x8 b0 = *(const bf16x8*)(Bs[p] + ib0);
        bf16x8 b1 = *(const bf16x8*)(Bs[p] + ib1);

        acc[0][0] = __builtin_amdgcn_mfma_f32_16x16x32_bf16(a0, b0, acc[0][0], 0, 0, 0);
        acc[0][1] = __builtin_amdgcn_mfma_f32_16x16x32_bf16(a0, b1, acc[0][1], 0, 0, 0);
        acc[1][0] = __builtin_amdgcn_mfma_f32_16x16x32_bf16(a1, b0, acc[1][0], 0, 0, 0);
        acc[1][1] = __builtin_amdgcn_mfma_f32_16x16x32_bf16(a1, b1, acc[1][1], 0, 0, 0);

        if (more) {
            *(u16x8*)(As[p ^ 1] + stIdx) = ra;
            *(u16x8*)(Bs[p ^ 1] + stIdx) = rb;
        }
        __syncthreads();
    }

    #pragma unroll
    for (int mi = 0; mi < 2; ++mi)
        #pragma unroll
        for (int ni = 0; ni < 2; ++ni)
            #pragma unroll
            for (int r = 0; r < 4; ++r) {
                int gm = m0 + wm + mi * 16 + quad * 4 + r;
                int gn = n0 + wn + ni * 16 + l15;
                V[((size_t)b * 256 + gm) * 1024 + gn] = acc[mi][ni][r] + bias[gm];
            }
}

// ---------- K3: fused bilinear-upsample + per-pixel cosine (v2, verified 220.5 µs config) ----------
__global__ void __launch_bounds__(256) fused_cos(const float* __restrict__ xcnn, // [8][256][128][128]
                                                 const float* __restrict__ V,    // [8][256][32][32]
                                                 float* __restrict__ out) {      // [8][1][128][128]
    __shared__ float red[8 * 385];   // [cs][ (q*4+px)*3 + j ], stride 385 breaks conflicts

    int bh = blockIdx.x;
    int b  = bh >> 7;
    int h  = bh & 127;
    int t  = threadIdx.x;
    int q  = t & 31;     // w-quad: pixels 4q..4q+3
    int cs = t >> 5;     // channel slice: channels cs*32..cs*32+31

    // ----- row interpolation (same for all 4 pixels of this thread) -----
    float sy = (h + 0.5f) * 0.25f - 0.5f;
    float fy = floorf(sy);
    float dy = sy - fy;
    int y0 = max(0, min(31, (int)fy));
    int y1 = max(0, min(31, (int)fy + 1));

    // ----- column weights per pixel, folded with edge clamp -----
    int cb = max(0, min(28, q - 1));      // float4 base col, covers all needed cols
    float a[4][4];
    #pragma unroll
    for (int px = 0; px < 4; ++px) {
        #pragma unroll
        for (int j = 0; j < 4; ++j) a[px][j] = 0.f;
        int w = q * 4 + px;
        float sx = (w + 0.5f) * 0.25f - 0.5f;
        float fx = floorf(sx);
        float dx = sx - fx;
        int x0 = max(0, min(31, (int)fx));
        int x1 = max(0, min(31, (int)fx + 1));
        a[px][x0 - cb] += 1.f - dx;
        a[px][x1 - cb] += dx;
    }

    const float* xp = xcnn + ((size_t)(b * 256 + cs * 32) * 16384) + h * 128 + q * 4;
    const float* vt = V + ((size_t)(b * 256 + cs * 32) * 1024) + y0 * 32 + cb;
    const float* vb = V + ((size_t)(b * 256 + cs * 32) * 1024) + y1 * 32 + cb;
    float ry = dy, ry0 = 1.f - dy;

    float dot[4] = {0.f, 0.f, 0.f, 0.f};
    float nx [4] = {0.f, 0.f, 0.f, 0.f};
    float nv [4] = {0.f, 0.f, 0.f, 0.f};

    #pragma unroll 8
    for (int c = 0; c < 32; ++c) {
        float4  xv  = *(const float4*)(xp + (size_t)c * 16384);
        f32x4u  top = *(const f32x4u*)(vt + (size_t)c * 1024);
        f32x4u  bot = *(const f32x4u*)(vb + (size_t)c * 1024);
        float bl0 = ry0 * top[0] + ry * bot[0];
        float bl1 = ry0 * top[1] + ry * bot[1];
        float bl2 = ry0 * top[2] + ry * bot[2];
        float bl3 = ry0 * top[3] + ry * bot[3];
        float xs[4] = {xv.x, xv.y, xv.z, xv.w};
        #pragma unroll
        for (int px = 0; px < 4; ++px) {
            float v = a[px][0] * bl0 + a[px][1] * bl1 + a[px][2] * bl2 + a[px][3] * bl3;
            dot[px] += xs[px] * v;
            nx [px] += xs[px] * xs[px];
            nv [px] += v * v;
        }
    }

    // ----- cross-slice reduction in LDS -----
    float* my = red + cs * 385;
    #pragma unroll
    for (int px = 0; px < 4; ++px) {
        int o = (q * 4 + px) * 3;
        my[o + 0] = dot[px];
        my[o + 1] = nx[px];
        my[o + 2] = nv[px];
    }
    __syncthreads();

    if (t < 128) {                 // one thread per output pixel of this row
        int px = t & 3;
        int q2 = t >> 2;
        int o  = (q2 * 4 + px) * 3;
        float d = 0.f, sx2 = 0.f, sv2 = 0.f;
        #pragma unroll
        for (int s = 0; s < 8; ++s) {
            d   += red[s * 385 + o + 0];
            sx2 += red[s * 385 + o + 1];
            sv2 += red[s * 385 + o + 2];
        }
        out[(size_t)b * 16384 + h * 128 + q2 * 4 + px] =
            d / (sqrtf(sx2) * sqrtf(sv2) + 1e-8f);
    }
}

extern "C" void kernel_launch(void* const* d_in, const int* in_sizes, int n_in,
                              void* d_out, int out_size, void* d_ws, size_t ws_size,
                              hipStream_t stream) {
    const float* x_cnn = (const float*)d_in[0];  // [8][256][128][128]
    const float* x_vit = (const float*)d_in[1];  // [8][512][32][32]
    const float* W     = (const float*)d_in[2];  // [256][512]
    const float* bias  = (const float*)d_in[3];  // [256]
    float* out = (float*)d_out;                  // [8][1][128][128] fp32

    char* ws = (char*)d_ws;
    float*          V   = (float*)ws;                         // 8*256*1024 f32  = 8 MB
    unsigned short* Xt  = (unsigned short*)(ws + 8388608);    // 8*1024*512 bf16 = 8 MB
    unsigned short* Wbf = (unsigned short*)(ws + 16777216);   // 256*512 bf16    = 256 KB

    prep<<<1152, 256, 0, stream>>>(x_vit, Xt, W, Wbf);
    gemm_bf16<<<dim3(16, 4, 8), 256, 0, stream>>>(Wbf, Xt, bias, V);
    fused_cos<<<1024, 256, 0, stream>>>(x_cnn, V, out);
}